// Round 1
// baseline (325.097 us; speedup 1.0000x reference)
//
#include <hip/hip_runtime.h>

#define TLEN 1000000
#define YS 64
#define XS 50000
#define CHUNK 248              // steps per chunk (multiple of 8)
#define WARM 64                // warm-up steps (multiple of 8)
#define NWAVES ((TLEN + CHUNK - 1) / CHUNK)   // 4033
#define WPB 4                  // waves per block (256 threads)

__device__ __forceinline__ float rl(float v, int i) {
  return __uint_as_float(__builtin_amdgcn_readlane(__float_as_uint(v), i));
}

__device__ __forceinline__ float wave_sum(float v) {
#pragma unroll
  for (int off = 32; off; off >>= 1) v += __shfl_xor(v, off, 64);
  return v;
}

__device__ __forceinline__ long clampT(long t) {
  return t > (long)(TLEN - 1) ? (long)(TLEN - 1) : t;
}

template <bool USE_BT>
__device__ __forceinline__ float eload(const float* __restrict__ bsrc, int xt, int lane) {
  return USE_BT ? bsrc[(size_t)xt * YS + lane] : bsrc[(size_t)lane * XS + xt];
}

// One recurrence step at time t using ring slot u.
// er[u] holds e_t = b[:, x[t]] (this lane's element); sx[u] holds x[t+8].
template <bool USE_BT, bool STORE>
__device__ __forceinline__ void one_step(long t, int u, float& alpha,
    const float (&a)[YS], float (&er)[8], int (&sx)[8],
    const int* __restrict__ x, const float* __restrict__ bsrc,
    float* __restrict__ out, int lane)
{
  float e = er[u];
  float s0 = 0.f, s1 = 0.f, s2 = 0.f, s3 = 0.f;
#pragma unroll
  for (int i = 0; i < YS; i += 4) {
    s0 = fmaf(rl(alpha, i + 0), a[i + 0], s0);
    s1 = fmaf(rl(alpha, i + 1), a[i + 1], s1);
    s2 = fmaf(rl(alpha, i + 2), a[i + 2], s2);
    s3 = fmaf(rl(alpha, i + 3), a[i + 3], s3);
  }
  float v = ((s0 + s1) + (s2 + s3)) * e;
  float s = wave_sum(v);
  alpha = v * __builtin_amdgcn_rcpf(s);
  if (STORE) out[(size_t)t * YS + lane] = alpha;
  // refill ring for t+8
  er[u] = eload<USE_BT>(bsrc, sx[u], lane);
  sx[u] = x[clampT(t + 16)];
}

template <bool USE_BT, bool STORE>
__device__ __forceinline__ void run_steps(long tstart, int count, float& alpha,
    const float (&a)[YS], float (&er)[8], int (&sx)[8],
    const int* __restrict__ x, const float* __restrict__ bsrc,
    float* __restrict__ out, int lane)
{
  int nfull = count & ~7;
  long t = tstart;
  for (int blk = 0; blk < nfull; blk += 8) {
#pragma unroll
    for (int u = 0; u < 8; u++)
      one_step<USE_BT, STORE>(t + u, u, alpha, a, er, sx, x, bsrc, out, lane);
    t += 8;
  }
  int rem = count & 7;
#pragma unroll
  for (int u = 0; u < 8; u++)
    if (u < rem)
      one_step<USE_BT, STORE>(t + u, u, alpha, a, er, sx, x, bsrc, out, lane);
}

template <bool USE_BT>
__global__ __launch_bounds__(256, 4) void hmm_fwd(
    const int* __restrict__ x, const float* __restrict__ A,
    const float* __restrict__ pi, const float* __restrict__ bsrc,
    float* __restrict__ out)
{
  int wv = blockIdx.x * WPB + (threadIdx.x >> 6);
  int lane = threadIdx.x & 63;
  if (wv >= NWAVES) return;

  // transition column for this lane: a[i] = A[i][lane]
  float a[YS];
#pragma unroll
  for (int i = 0; i < YS; i++) a[i] = A[i * YS + lane];

  long t0 = (long)wv * CHUNK;
  long tend = t0 + CHUNK;
  if (tend > TLEN) tend = TLEN;

  float alpha;
  long ts;          // first recurrence step index
  if (wv == 0) {
    int x0 = x[0];
    float e0 = eload<USE_BT>(bsrc, x0, lane);
    float v = e0 * pi[lane];
    float s = wave_sum(v);
    alpha = v * __builtin_amdgcn_rcpf(s);
    out[lane] = alpha;           // row 0
    ts = 1;
  } else {
    alpha = 1.0f / 64.0f;        // uniform start; warm-up forgets it
    ts = t0 - WARM;
  }

  // prologue: fill emission ring for [ts, ts+8) and x ring with x[ts+8 ..)
  float er[8];
  int sx[8];
#pragma unroll
  for (int u = 0; u < 8; u++) {
    int xt = x[clampT(ts + u)];
    er[u] = eload<USE_BT>(bsrc, xt, lane);
    sx[u] = x[clampT(ts + 8 + u)];
  }

  if (wv == 0) {
    run_steps<USE_BT, true>(1, (int)(tend - 1), alpha, a, er, sx, x, bsrc, out, lane);
  } else {
    run_steps<USE_BT, false>(ts, WARM, alpha, a, er, sx, x, bsrc, out, lane);
    run_steps<USE_BT, true>(t0, (int)(tend - t0), alpha, a, er, sx, x, bsrc, out, lane);
  }
}

// 64x64-tile transpose of b (YS x XS) into bT (XS x YS)
__global__ __launch_bounds__(256) void transpose_b(
    const float* __restrict__ b, float* __restrict__ bT)
{
  __shared__ float tile[64][65];
  int x0 = blockIdx.x << 6;
  int lane = threadIdx.x & 63;
  int w = threadIdx.x >> 6;   // 0..3
  int xg = x0 + lane;
#pragma unroll
  for (int yy = 0; yy < 64; yy += 4) {
    int y = yy + w;
    tile[y][lane] = (xg < XS) ? b[(size_t)y * XS + xg] : 0.f;
  }
  __syncthreads();
#pragma unroll
  for (int xx = 0; xx < 64; xx += 4) {
    int xcur = x0 + xx + w;
    if (xcur < XS) bT[(size_t)xcur * YS + lane] = tile[lane][xx + w];
  }
}

extern "C" void kernel_launch(void* const* d_in, const int* in_sizes, int n_in,
                              void* d_out, int out_size, void* d_ws, size_t ws_size,
                              hipStream_t stream)
{
  const int*   x  = (const int*)d_in[0];
  const float* A  = (const float*)d_in[1];
  const float* b  = (const float*)d_in[2];
  const float* pi = (const float*)d_in[3];
  float* out = (float*)d_out;

  const size_t bt_bytes = (size_t)XS * YS * sizeof(float);
  int blocks = (NWAVES + WPB - 1) / WPB;

  if (ws_size >= bt_bytes) {
    float* bT = (float*)d_ws;
    int tblocks = (XS + 63) / 64;
    transpose_b<<<tblocks, 256, 0, stream>>>(b, bT);
    hmm_fwd<true><<<blocks, 256, 0, stream>>>(x, A, pi, bT, out);
  } else {
    hmm_fwd<false><<<blocks, 256, 0, stream>>>(x, A, pi, b, out);
  }
}